// Round 1
// baseline (77.815 us; speedup 1.0000x reference)
//
#include <hip/hip_runtime.h>

// TransientCombNoise: B=32, T=2000, BLOCK=64, SR=16000, MAX_DELAY=480
// N = B*T = 64000 rows, 64 samples each.
//
// Math collapse: delay = int(64*(0.5+0.5*bw)), bw in [0.05,1) => delay in [33,63].
// Since 2*delay >= 66 > 63, the comb feedback recursion y[s] = x[s]+tilt*y[s-delay]
// has depth at most 1 within the 64-sample block:
//   y[s] = x[s] + tilt * (s >= delay ? x[s-delay] : 0)
// with x[s] = noise[s] * exp(-s/attack_samples) * energy.
// Then out = y / sqrt(mean(y^2) + 1e-5).

#define NROWS 64000

__global__ __launch_bounds__(256) void TransientCombNoise_kernel(
    const float* __restrict__ params,   // [NROWS, 4]
    const float* __restrict__ noise,    // [NROWS, 64]
    float* __restrict__ out)            // [NROWS, 64]
{
    const int wave  = threadIdx.x >> 6;       // 4 waves per block
    const int lane  = threadIdx.x & 63;       // sample index s
    const int row   = blockIdx.x * 4 + wave;  // grid sized exactly: 16000*4 = 64000

    // Broadcast load of the 4 per-row params (same 16B for all 64 lanes -> L1 broadcast)
    const float4 p = ((const float4*)params)[row];

    // attack_samples = clip((0.0005 + p0*0.0495)*16000, 1, inf)  (mathematically >= 8)
    float attack_samples = (0.0005f + p.x * 0.0495f) * 16000.0f;
    attack_samples = fmaxf(attack_samples, 1.0f);
    const float energy = p.y;
    const float tilt   = p.z * 2.0f - 1.0f;
    const float bandwidth = 0.05f + p.w * 0.95f;
    int delay = (int)(64.0f * (0.5f + 0.5f * bandwidth));   // trunc toward 0, like astype(int32)
    delay = max(1, min(delay, 480));

    // x[s] = noise * exp(-s/attack) * energy   (coalesced 4B/lane load)
    const float n   = noise[row * 64 + lane];
    const float env = expf(-(float)lane / attack_samples);
    const float x   = n * env * energy;

    // Single-tap comb via cross-lane shuffle (all lanes participate; gate result)
    const int src = lane - delay;
    const float xd = __shfl(x, src < 0 ? 0 : src, 64);
    const float y  = x + tilt * (src >= 0 ? xd : 0.0f);

    // Wave-wide sum of y^2 (butterfly over 64 lanes)
    float ss = y * y;
    #pragma unroll
    for (int off = 32; off > 0; off >>= 1)
        ss += __shfl_xor(ss, off, 64);

    const float rms = sqrtf(ss * (1.0f / 64.0f) + 1e-5f);
    out[row * 64 + lane] = y / rms;
}

extern "C" void kernel_launch(void* const* d_in, const int* in_sizes, int n_in,
                              void* d_out, int out_size, void* d_ws, size_t ws_size,
                              hipStream_t stream) {
    const float* params = (const float*)d_in[0];  // [B,T,4] = [64000,4]
    const float* noise  = (const float*)d_in[1];  // [B,T,64] = [64000,64]
    float* out          = (float*)d_out;          // [B, T*64] = 4,096,000 floats

    // 64000 rows, 1 wave (64 lanes) per row, 4 waves per 256-thread block
    TransientCombNoise_kernel<<<dim3(NROWS / 4), dim3(256), 0, stream>>>(params, noise, out);
}

// Round 2
// 72.941 us; speedup vs baseline: 1.0668x; 1.0668x over previous
//
#include <hip/hip_runtime.h>

// TransientCombNoise: B=32, T=2000, BLOCK=64 -> N = 64000 rows x 64 samples.
//
// Math collapse (verified passing in R1): delay in [33,63], so comb recursion
// depth <= 1 within the 64-sample block:
//   y[s] = x[s] + tilt * (s >= delay ? x[s-delay] : 0),
//   x[s] = noise[s] * exp(-s/attack) * energy,  out = y / sqrt(mean(y^2)+1e-5).
//
// R2 layout: float4 per lane (16 B/lane loads/stores). 16 lanes per row,
// 4 rows per wave, 4 waves per block -> 16 rows/block, 4000 blocks.
// Comb tap: t = s - delay has t mod 4 = (j - delay) mod 4 = e, uniform per row,
// and j -> e is a bijection; so each lane selects its own x[e] and ONE __shfl
// per output element j fetches the delayed sample from lane rowBase + (t>>2).

#define NROWS 64000

__global__ __launch_bounds__(256) void TransientCombNoise_kernel(
    const float4* __restrict__ params,   // [NROWS] float4
    const float4* __restrict__ noise4,   // [NROWS*16] float4
    float4* __restrict__ out4)           // [NROWS*16] float4
{
    const int lane      = threadIdx.x & 63;
    const int waveInBlk = threadIdx.x >> 6;        // 0..3
    const int rowInWave = lane >> 4;               // 0..3
    const int chunk     = lane & 15;               // 0..15 -> samples 4c..4c+3
    const int row       = (blockIdx.x * 4 + waveInBlk) * 4 + rowInWave;
    const int rowBase   = rowInWave << 4;          // first lane of this row's group

    // Per-row params (broadcast across the 16 lanes of the row group)
    const float4 p = params[row];
    const float attack = fmaxf((0.0005f + p.x * 0.0495f) * 16000.0f, 1.0f);
    const float c      = -1.44269504088896f / attack;   // exp(-s/a) = exp2(s*c)
    const float energy = p.y;
    const float tilt   = p.z * 2.0f - 1.0f;
    const float bw     = 0.05f + p.w * 0.95f;
    int delay = (int)(64.0f * (0.5f + 0.5f * bw));      // trunc, in [33,63]
    delay = max(1, min(delay, 480));

    // x[j] = noise * envelope * energy  (16 B coalesced load)
    const float4 nz = noise4[row * 16 + chunk];
    const int s0 = chunk << 2;
    float x[4];
    x[0] = nz.x * exp2f((float)(s0 + 0) * c) * energy;
    x[1] = nz.y * exp2f((float)(s0 + 1) * c) * energy;
    x[2] = nz.z * exp2f((float)(s0 + 2) * c) * energy;
    x[3] = nz.w * exp2f((float)(s0 + 3) * c) * energy;

    // Single-tap comb: one shuffle per output element
    float y[4];
    #pragma unroll
    for (int j = 0; j < 4; ++j) {
        const int t = s0 + j - delay;               // source sample index
        const int e = (j - delay) & 3;              // row-uniform source element
        const float val = (e == 0) ? x[0] : (e == 1) ? x[1] : (e == 2) ? x[2] : x[3];
        const int srcLane = rowBase + ((t >= 0) ? (t >> 2) : 0);
        const float f = __shfl(val, srcLane, 64);
        y[j] = x[j] + ((t >= 0) ? tilt * f : 0.0f);
    }

    // Sum of y^2 across the 16 lanes of this row (xor masks 1,2,4,8 stay in-group)
    float ss = y[0]*y[0] + y[1]*y[1] + y[2]*y[2] + y[3]*y[3];
    #pragma unroll
    for (int off = 1; off < 16; off <<= 1)
        ss += __shfl_xor(ss, off, 64);

    const float inv = 1.0f / sqrtf(ss * (1.0f / 64.0f) + 1e-5f);
    out4[row * 16 + chunk] = make_float4(y[0]*inv, y[1]*inv, y[2]*inv, y[3]*inv);
}

extern "C" void kernel_launch(void* const* d_in, const int* in_sizes, int n_in,
                              void* d_out, int out_size, void* d_ws, size_t ws_size,
                              hipStream_t stream) {
    const float4* params = (const float4*)d_in[0];  // [64000,4]
    const float4* noise  = (const float4*)d_in[1];  // [64000,64] as float4
    float4* out          = (float4*)d_out;          // [64000,64] as float4

    // 16 rows per 256-thread block -> 4000 blocks
    TransientCombNoise_kernel<<<dim3(NROWS / 16), dim3(256), 0, stream>>>(params, noise, out);
}